// Round 9
// baseline (112.978 us; speedup 1.0000x reference)
//
#include <hip/hip_runtime.h>
#include <math.h>

// Problem constants (match reference)
#define BB 64
#define DD 1024
#define GG 64
#define F4 (DD / 4)        // 256 float4 per row
#define ROWS 2             // u-rows per wave
#define WAVES_PB 4         // waves per block
#define U_PER_BLOCK (ROWS * WAVES_PB)          // 8
#define BLOCKS_PER_B (DD / U_PER_BLOCK)        // 128
#define NWG (BB * BLOCKS_PER_B)                // 8192

typedef float fvec4 __attribute__((ext_vector_type(4)));

__device__ __forceinline__ float softplus_fast(float z) {
    // softplus(z) = max(z,0) + ln2 * log2(1 + exp(-|z|))
    const float LOG2E = 1.44269504088896340736f;
    const float LN2   = 0.69314718055994530942f;
    float t = __builtin_amdgcn_exp2f(-LOG2E * fabsf(z));   // v_exp_f32
    float l = __builtin_amdgcn_logf(1.0f + t);             // v_log_f32 (log2)
    return fmaxf(z, 0.0f) + LN2 * l;
}

// No min-waves arg: do NOT push the allocator toward high occupancy —
// we deliberately spend ~130 VGPR to keep 28 loads in flight per wave.
__global__ __launch_bounds__(256) void mld_kernel(
    const float* __restrict__ x, const int* __restrict__ gid,
    const float* __restrict__ w_mu, const float* __restrict__ w_sigma,
    const float* __restrict__ b_mu, const float* __restrict__ b_sigma,
    const float* __restrict__ eps_w, const float* __restrict__ eps_b,
    float* __restrict__ out)
{
    const int lane = (int)(threadIdx.x & 63);
    const int wid  = (int)(threadIdx.x >> 6);          // 0..3

    // Natural block order (round-5 swizzle regressed; keep hardware mapping).
    const int logical = (int)blockIdx.x;
    const int b    = logical >> 7;                     // BLOCKS_PER_B = 128
    const int ublk = logical & 127;
    const int u0   = ublk * U_PER_BLOCK + wid * ROWS;  // wave's first u row
    const int g    = gid[b];

    const fvec4* __restrict__ xr  = (const fvec4*)(x + (size_t)b * DD);
    const fvec4* __restrict__ wmr = (const fvec4*)(w_mu    + ((size_t)g * DD + u0) * DD);
    const fvec4* __restrict__ wsr = (const fvec4*)(w_sigma + ((size_t)g * DD + u0) * DD);
    const fvec4* __restrict__ ewr = (const fvec4*)(eps_w   + ((size_t)b * DD + u0) * DD);

    // Issue ALL 28 loads (7 streams x 4 k-steps) before consuming anything.
    fvec4 X[4], WM0[4], WS0[4], EW0[4], WM1[4], WS1[4], EW1[4];
    #pragma unroll
    for (int k = 0; k < 4; ++k) {
        const int i = lane + 64 * k;
        X[k]   = xr[i];
        WM0[k] = wmr[i];
        WS0[k] = wsr[i];
        EW0[k] = __builtin_nontemporal_load(ewr + i);        // once-only stream
        WM1[k] = wmr[F4 + i];
        WS1[k] = wsr[F4 + i];
        EW1[k] = __builtin_nontemporal_load(ewr + F4 + i);
    }
    // Pin: every load must complete before this point; none may sink into the
    // consume phase. One waitcnt per wave instead of ~28 (rule #17 idiom).
    asm volatile("" ::
        "v"(X[0]),   "v"(X[1]),   "v"(X[2]),   "v"(X[3]),
        "v"(WM0[0]), "v"(WM0[1]), "v"(WM0[2]), "v"(WM0[3]),
        "v"(WS0[0]), "v"(WS0[1]), "v"(WS0[2]), "v"(WS0[3]),
        "v"(EW0[0]), "v"(EW0[1]), "v"(EW0[2]), "v"(EW0[3]),
        "v"(WM1[0]), "v"(WM1[1]), "v"(WM1[2]), "v"(WM1[3]),
        "v"(WS1[0]), "v"(WS1[1]), "v"(WS1[2]), "v"(WS1[3]),
        "v"(EW1[0]), "v"(EW1[1]), "v"(EW1[2]), "v"(EW1[3]));

    float a0 = 0.f, a1 = 0.f;
    #pragma unroll
    for (int k = 0; k < 4; ++k) {
        a0 += (WM0[k].x + softplus_fast(WS0[k].x) * EW0[k].x) * X[k].x;
        a0 += (WM0[k].y + softplus_fast(WS0[k].y) * EW0[k].y) * X[k].y;
        a0 += (WM0[k].z + softplus_fast(WS0[k].z) * EW0[k].z) * X[k].z;
        a0 += (WM0[k].w + softplus_fast(WS0[k].w) * EW0[k].w) * X[k].w;
        a1 += (WM1[k].x + softplus_fast(WS1[k].x) * EW1[k].x) * X[k].x;
        a1 += (WM1[k].y + softplus_fast(WS1[k].y) * EW1[k].y) * X[k].y;
        a1 += (WM1[k].z + softplus_fast(WS1[k].z) * EW1[k].z) * X[k].z;
        a1 += (WM1[k].w + softplus_fast(WS1[k].w) * EW1[k].w) * X[k].w;
    }

    // 2 independent butterfly reductions (all lanes end with the row sums)
    #pragma unroll
    for (int off = 32; off > 0; off >>= 1) {
        a0 += __shfl_xor(a0, off, 64);
        a1 += __shfl_xor(a1, off, 64);
    }

    // lanes 0..1 each handle one row's bias + relu + store
    if (lane < ROWS) {
        const int u = u0 + lane;
        const size_t gu = (size_t)g * DD + u;
        const size_t bu = (size_t)b * DD + u;
        const float eb = __builtin_nontemporal_load(eps_b + bu);
        const float bs = b_mu[gu] + softplus_fast(b_sigma[gu]) * eb;
        const float o = (lane == 0 ? a0 : a1) + bs;
        out[bu] = fmaxf(o, 0.0f);
    }
}

extern "C" void kernel_launch(void* const* d_in, const int* in_sizes, int n_in,
                              void* d_out, int out_size, void* d_ws, size_t ws_size,
                              hipStream_t stream) {
    const float* x       = (const float*)d_in[0];
    const int*   gid     = (const int*)d_in[1];
    const float* w_mu    = (const float*)d_in[2];
    const float* w_sigma = (const float*)d_in[3];
    const float* b_mu    = (const float*)d_in[4];
    const float* b_sigma = (const float*)d_in[5];
    const float* eps_w   = (const float*)d_in[6];
    const float* eps_b   = (const float*)d_in[7];
    float* out = (float*)d_out;

    mld_kernel<<<NWG, 256, 0, stream>>>(x, gid, w_mu, w_sigma, b_mu, b_sigma,
                                        eps_w, eps_b, out);
}

// Round 10
// 99.455 us; speedup vs baseline: 1.1360x; 1.1360x over previous
//
#include <hip/hip_runtime.h>
#include <math.h>

// Problem constants (match reference)
#define BB 64
#define DD 1024
#define GG 64
#define F4 (DD / 4)            // 256 float4 per row
#define UPB 8                  // u-rows per block (4 waves x 2 rows)
#define BLOCKS_PER_G (DD / UPB)   // 128
#define NWG (GG * BLOCKS_PER_G)   // 8192

typedef float fvec4 __attribute__((ext_vector_type(4)));

__device__ __forceinline__ float softplus_fast(float z) {
    // softplus(z) = max(z,0) + ln2 * log2(1 + exp(-|z|))
    const float LOG2E = 1.44269504088896340736f;
    const float LN2   = 0.69314718055994530942f;
    float t = __builtin_amdgcn_exp2f(-LOG2E * fabsf(z));   // v_exp_f32
    float l = __builtin_amdgcn_logf(1.0f + t);             // v_log_f32 (log2)
    return fmaxf(z, 0.0f) + LN2 * l;
}

// Pass 1: per-group sample lists. ws[0..63] = counts, ws[64 + g*64 + i] = sample ids.
__global__ void build_lists(const int* __restrict__ gid,
                            int* __restrict__ counts, int* __restrict__ lists) {
    const int g = (int)threadIdx.x;
    if (g < GG) {
        int c = 0;
        for (int b = 0; b < BB; ++b)
            if (gid[b] == g) lists[g * BB + (c++)] = b;
        counts[g] = c;
    }
}

// Pass 2: block = (group g, u-chunk). Load w chunk ONCE, precompute softplus ONCE,
// then stream x/eps for every sample of this group. Each w byte is requested by
// exactly one block -> removes ~190 MB of duplicate w traffic into L2.
__global__ __launch_bounds__(256) void mld_group_kernel(
    const float* __restrict__ x,
    const int* __restrict__ counts, const int* __restrict__ lists,
    const float* __restrict__ w_mu, const float* __restrict__ w_sigma,
    const float* __restrict__ b_mu, const float* __restrict__ b_sigma,
    const float* __restrict__ eps_w, const float* __restrict__ eps_b,
    float* __restrict__ out)
{
    const int lane = (int)(threadIdx.x & 63);
    const int wid  = (int)(threadIdx.x >> 6);       // 0..3
    const int g    = (int)blockIdx.x >> 7;          // BLOCKS_PER_G = 128
    const int ublk = (int)blockIdx.x & 127;
    const int n    = counts[g];
    if (n == 0) return;                             // empty group: no w loads
    const int u0   = ublk * UPB + wid * 2;          // this wave's 2 rows

    const fvec4* __restrict__ wmr = (const fvec4*)(w_mu    + ((size_t)g * DD + u0) * DD);
    const fvec4* __restrict__ wsr = (const fvec4*)(w_sigma + ((size_t)g * DD + u0) * DD);

    // w chunk for 2 rows, held in registers for the whole sample loop.
    fvec4 WM0[4], WM1[4], SP0[4], SP1[4];
    #pragma unroll
    for (int k = 0; k < 4; ++k) {
        const int i = lane + 64 * k;
        WM0[k] = wmr[i];
        WM1[k] = wmr[F4 + i];
        fvec4 s0 = wsr[i];
        fvec4 s1 = wsr[F4 + i];
        SP0[k].x = softplus_fast(s0.x); SP0[k].y = softplus_fast(s0.y);
        SP0[k].z = softplus_fast(s0.z); SP0[k].w = softplus_fast(s0.w);
        SP1[k].x = softplus_fast(s1.x); SP1[k].y = softplus_fast(s1.y);
        SP1[k].z = softplus_fast(s1.z); SP1[k].w = softplus_fast(s1.w);
    }

    for (int s = 0; s < n; ++s) {
        const int b = lists[g * BB + s];            // block-uniform scalar load
        const fvec4* __restrict__ xr  = (const fvec4*)(x     + (size_t)b * DD);
        const fvec4* __restrict__ ewr = (const fvec4*)(eps_w + ((size_t)b * DD + u0) * DD);

        float a0 = 0.f, a1 = 0.f;
        #pragma unroll
        for (int k = 0; k < 4; ++k) {
            const int i = lane + 64 * k;
            const fvec4 xm = xr[i];
            const fvec4 e0 = __builtin_nontemporal_load(ewr + i);       // once-only
            const fvec4 e1 = __builtin_nontemporal_load(ewr + F4 + i);
            a0 += (WM0[k].x + SP0[k].x * e0.x) * xm.x;
            a0 += (WM0[k].y + SP0[k].y * e0.y) * xm.y;
            a0 += (WM0[k].z + SP0[k].z * e0.z) * xm.z;
            a0 += (WM0[k].w + SP0[k].w * e0.w) * xm.w;
            a1 += (WM1[k].x + SP1[k].x * e1.x) * xm.x;
            a1 += (WM1[k].y + SP1[k].y * e1.y) * xm.y;
            a1 += (WM1[k].z + SP1[k].z * e1.z) * xm.z;
            a1 += (WM1[k].w + SP1[k].w * e1.w) * xm.w;
        }

        // 2 independent butterfly reductions
        #pragma unroll
        for (int off = 32; off > 0; off >>= 1) {
            a0 += __shfl_xor(a0, off, 64);
            a1 += __shfl_xor(a1, off, 64);
        }

        if (lane < 2) {
            const int u = u0 + lane;
            const size_t gu = (size_t)g * DD + u;
            const size_t bu = (size_t)b * DD + u;
            const float eb = __builtin_nontemporal_load(eps_b + bu);
            const float bs = b_mu[gu] + softplus_fast(b_sigma[gu]) * eb;
            const float o = (lane == 0 ? a0 : a1) + bs;
            out[bu] = fmaxf(o, 0.0f);
        }
    }
}

extern "C" void kernel_launch(void* const* d_in, const int* in_sizes, int n_in,
                              void* d_out, int out_size, void* d_ws, size_t ws_size,
                              hipStream_t stream) {
    const float* x       = (const float*)d_in[0];
    const int*   gid     = (const int*)d_in[1];
    const float* w_mu    = (const float*)d_in[2];
    const float* w_sigma = (const float*)d_in[3];
    const float* b_mu    = (const float*)d_in[4];
    const float* b_sigma = (const float*)d_in[5];
    const float* eps_w   = (const float*)d_in[6];
    const float* eps_b   = (const float*)d_in[7];
    float* out = (float*)d_out;

    int* counts = (int*)d_ws;            // [64]
    int* lists  = counts + GG;           // [64][64]

    build_lists<<<1, 64, 0, stream>>>(gid, counts, lists);
    mld_group_kernel<<<NWG, 256, 0, stream>>>(x, counts, lists, w_mu, w_sigma,
                                              b_mu, b_sigma, eps_w, eps_b, out);
}

// Round 11
// 98.836 us; speedup vs baseline: 1.1431x; 1.0063x over previous
//
#include <hip/hip_runtime.h>
#include <math.h>

// Problem constants (match reference)
#define BB 64
#define DD 1024
#define GG 64
#define F4 (DD / 4)               // 256 float4 per row
#define ROWS 2                    // u-rows per wave
#define UPB 8                     // u-rows per block (4 waves x 2 rows)
#define BLOCKS_PER_B (DD / UPB)   // 128
#define NWG (BB * BLOCKS_PER_B)   // 8192

typedef float fvec4 __attribute__((ext_vector_type(4)));

__device__ __forceinline__ float softplus_fast(float z) {
    // softplus(z) = max(z,0) + ln2 * log2(1 + exp(-|z|))
    const float LOG2E = 1.44269504088896340736f;
    const float LN2   = 0.69314718055994530942f;
    float t = __builtin_amdgcn_exp2f(-LOG2E * fabsf(z));   // v_exp_f32
    float l = __builtin_amdgcn_logf(1.0f + t);             // v_log_f32 (log2)
    return fmaxf(z, 0.0f) + LN2 * l;
}

// Pass 1: sorted[0..63] = sample ids ordered by group (one 64-lane wave).
// Same-group samples become ADJACENT slots -> their blocks co-resident ->
// w-chunk requests hit L2 (XCD of block = ublk%8, invariant across slots).
__global__ void build_sorted(const int* __restrict__ gid, int* __restrict__ sorted) {
    const int g = (int)threadIdx.x;        // thread g handles group g
    int cnt = 0;
    for (int b = 0; b < BB; ++b) cnt += (gid[b] == g) ? 1 : 0;
    // exclusive prefix sum across the wave
    int pre = cnt;
    #pragma unroll
    for (int d = 1; d < 64; d <<= 1) {
        int t = __shfl_up(pre, d, 64);
        if (g >= d) pre += t;
    }
    int off = pre - cnt;
    for (int b = 0; b < BB; ++b)
        if (gid[b] == g) sorted[off++] = b;
}

// Pass 2: block = (slot, u-chunk); slot -> group-sorted sample. Uniform work
// per block (no empty blocks, no sample loop) + w dedup via L2 temporal reuse.
__global__ __launch_bounds__(256) void mld_kernel(
    const float* __restrict__ x, const int* __restrict__ gid,
    const int* __restrict__ sorted,
    const float* __restrict__ w_mu, const float* __restrict__ w_sigma,
    const float* __restrict__ b_mu, const float* __restrict__ b_sigma,
    const float* __restrict__ eps_w, const float* __restrict__ eps_b,
    float* __restrict__ out)
{
    const int lane = (int)(threadIdx.x & 63);
    const int wid  = (int)(threadIdx.x >> 6);       // 0..3
    const int slot = (int)blockIdx.x >> 7;          // BLOCKS_PER_B = 128
    const int ublk = (int)blockIdx.x & 127;
    const int b    = sorted[slot];
    const int g    = gid[b];
    const int u0   = ublk * UPB + wid * ROWS;       // wave's first u row

    const fvec4* __restrict__ xr  = (const fvec4*)(x + (size_t)b * DD);
    const fvec4* __restrict__ wmr = (const fvec4*)(w_mu    + ((size_t)g * DD + u0) * DD);
    const fvec4* __restrict__ wsr = (const fvec4*)(w_sigma + ((size_t)g * DD + u0) * DD);
    const fvec4* __restrict__ ewr = (const fvec4*)(eps_w   + ((size_t)b * DD + u0) * DD);

    float a0 = 0.f, a1 = 0.f;
    #pragma unroll
    for (int k = 0; k < 4; ++k) {
        const int i = lane + 64 * k;
        const fvec4 xm = xr[i];
        const fvec4 wm0 = wmr[i];
        const fvec4 ws0 = wsr[i];
        const fvec4 e0  = __builtin_nontemporal_load(ewr + i);       // once-only
        const fvec4 wm1 = wmr[F4 + i];
        const fvec4 ws1 = wsr[F4 + i];
        const fvec4 e1  = __builtin_nontemporal_load(ewr + F4 + i);
        a0 += (wm0.x + softplus_fast(ws0.x) * e0.x) * xm.x;
        a0 += (wm0.y + softplus_fast(ws0.y) * e0.y) * xm.y;
        a0 += (wm0.z + softplus_fast(ws0.z) * e0.z) * xm.z;
        a0 += (wm0.w + softplus_fast(ws0.w) * e0.w) * xm.w;
        a1 += (wm1.x + softplus_fast(ws1.x) * e1.x) * xm.x;
        a1 += (wm1.y + softplus_fast(ws1.y) * e1.y) * xm.y;
        a1 += (wm1.z + softplus_fast(ws1.z) * e1.z) * xm.z;
        a1 += (wm1.w + softplus_fast(ws1.w) * e1.w) * xm.w;
    }

    // 2 independent butterfly reductions (all lanes end with the row sums)
    #pragma unroll
    for (int off = 32; off > 0; off >>= 1) {
        a0 += __shfl_xor(a0, off, 64);
        a1 += __shfl_xor(a1, off, 64);
    }

    // lanes 0..1 each handle one row's bias + relu + store
    if (lane < ROWS) {
        const int u = u0 + lane;
        const size_t gu = (size_t)g * DD + u;
        const size_t bu = (size_t)b * DD + u;
        const float eb = __builtin_nontemporal_load(eps_b + bu);
        const float bs = b_mu[gu] + softplus_fast(b_sigma[gu]) * eb;
        const float o = (lane == 0 ? a0 : a1) + bs;
        out[bu] = fmaxf(o, 0.0f);
    }
}

extern "C" void kernel_launch(void* const* d_in, const int* in_sizes, int n_in,
                              void* d_out, int out_size, void* d_ws, size_t ws_size,
                              hipStream_t stream) {
    const float* x       = (const float*)d_in[0];
    const int*   gid     = (const int*)d_in[1];
    const float* w_mu    = (const float*)d_in[2];
    const float* w_sigma = (const float*)d_in[3];
    const float* b_mu    = (const float*)d_in[4];
    const float* b_sigma = (const float*)d_in[5];
    const float* eps_w   = (const float*)d_in[6];
    const float* eps_b   = (const float*)d_in[7];
    float* out = (float*)d_out;

    int* sorted = (int*)d_ws;            // [64]

    build_sorted<<<1, 64, 0, stream>>>(gid, sorted);
    mld_kernel<<<NWG, 256, 0, stream>>>(x, gid, sorted, w_mu, w_sigma,
                                        b_mu, b_sigma, eps_w, eps_b, out);
}

// Round 13
// 95.427 us; speedup vs baseline: 1.1839x; 1.0357x over previous
//
#include <hip/hip_runtime.h>
#include <math.h>

// Problem constants (match reference)
#define BB 64
#define DD 1024
#define GG 64
#define F4 (DD / 4)               // 256 float4 per row
#define ROWS 2                    // u-rows per wave
#define UPB 8                     // u-rows per block (4 waves x 2 rows)
#define BLOCKS_PER_B (DD / UPB)   // 128
#define NWG (BB * BLOCKS_PER_B)   // 8192

typedef float fvec4 __attribute__((ext_vector_type(4)));

__device__ __forceinline__ float softplus_fast(float z) {
    // softplus(z) = max(z,0) + ln2 * log2(1 + exp(-|z|))
    const float LOG2E = 1.44269504088896340736f;
    const float LN2   = 0.69314718055994530942f;
    float t = __builtin_amdgcn_exp2f(-LOG2E * fabsf(z));   // v_exp_f32
    float l = __builtin_amdgcn_logf(1.0f + t);             // v_log_f32 (log2)
    return fmaxf(z, 0.0f) + LN2 * l;
}

// Single kernel: block = (slot, u-chunk). Wave 0 computes this block's sample
// id inline (stable sort-by-group rank via shfl; same mapping as the previous
// build_sorted kernel) -> no serial 1-block launch in the graph.
// Same-group samples occupy ADJACENT slots; XCD of a block = blockIdx%8 =
// f(ublk) only, so the same (g,ublk) w-chunk always lands on the same XCD's
// L2 and is fetched across the fabric ~once.
__global__ __launch_bounds__(256) void mld_kernel(
    const float* __restrict__ x, const int* __restrict__ gid,
    const float* __restrict__ w_mu, const float* __restrict__ w_sigma,
    const float* __restrict__ b_mu, const float* __restrict__ b_sigma,
    const float* __restrict__ eps_w, const float* __restrict__ eps_b,
    float* __restrict__ out)
{
    const int lane = (int)(threadIdx.x & 63);
    const int wid  = (int)(threadIdx.x >> 6);       // 0..3
    const int slot = (int)blockIdx.x >> 7;          // BLOCKS_PER_B = 128
    const int ublk = (int)blockIdx.x & 127;

    __shared__ int s_sample;
    if (wid == 0) {
        // lane l owns sample l; rank = position in stable group-sort
        const int gl = gid[lane];
        int rank = 0;
        #pragma unroll
        for (int d = 0; d < 64; ++d) {
            const int gd = __shfl(gl, d, 64);
            rank += (gd < gl || (gd == gl && d < lane)) ? 1 : 0;
        }
        if (rank == slot) s_sample = lane;          // exactly one lane matches
    }
    __syncthreads();
    const int b = s_sample;
    const int g = gid[b];
    const int u0 = ublk * UPB + wid * ROWS;         // wave's first u row

    const fvec4* __restrict__ xr  = (const fvec4*)(x + (size_t)b * DD);
    const fvec4* __restrict__ wmr = (const fvec4*)(w_mu    + ((size_t)g * DD + u0) * DD);
    const fvec4* __restrict__ wsr = (const fvec4*)(w_sigma + ((size_t)g * DD + u0) * DD);
    const fvec4* __restrict__ ewr = (const fvec4*)(eps_w   + ((size_t)b * DD + u0) * DD);

    float a0 = 0.f, a1 = 0.f;
    #pragma unroll
    for (int k = 0; k < 4; ++k) {
        const int i = lane + 64 * k;
        const fvec4 xm = xr[i];
        const fvec4 wm0 = wmr[i];
        const fvec4 ws0 = wsr[i];
        const fvec4 e0  = __builtin_nontemporal_load(ewr + i);       // once-only
        const fvec4 wm1 = wmr[F4 + i];
        const fvec4 ws1 = wsr[F4 + i];
        const fvec4 e1  = __builtin_nontemporal_load(ewr + F4 + i);
        a0 += (wm0.x + softplus_fast(ws0.x) * e0.x) * xm.x;
        a0 += (wm0.y + softplus_fast(ws0.y) * e0.y) * xm.y;
        a0 += (wm0.z + softplus_fast(ws0.z) * e0.z) * xm.z;
        a0 += (wm0.w + softplus_fast(ws0.w) * e0.w) * xm.w;
        a1 += (wm1.x + softplus_fast(ws1.x) * e1.x) * xm.x;
        a1 += (wm1.y + softplus_fast(ws1.y) * e1.y) * xm.y;
        a1 += (wm1.z + softplus_fast(ws1.z) * e1.z) * xm.z;
        a1 += (wm1.w + softplus_fast(ws1.w) * e1.w) * xm.w;
    }

    // 2 independent butterfly reductions (all lanes end with the row sums)
    #pragma unroll
    for (int off = 32; off > 0; off >>= 1) {
        a0 += __shfl_xor(a0, off, 64);
        a1 += __shfl_xor(a1, off, 64);
    }

    // lanes 0..1 each handle one row's bias + relu + store
    if (lane < ROWS) {
        const int u = u0 + lane;
        const size_t gu = (size_t)g * DD + u;
        const size_t bu = (size_t)b * DD + u;
        const float eb = __builtin_nontemporal_load(eps_b + bu);
        const float bs = b_mu[gu] + softplus_fast(b_sigma[gu]) * eb;
        const float o = (lane == 0 ? a0 : a1) + bs;
        out[bu] = fmaxf(o, 0.0f);
    }
}

extern "C" void kernel_launch(void* const* d_in, const int* in_sizes, int n_in,
                              void* d_out, int out_size, void* d_ws, size_t ws_size,
                              hipStream_t stream) {
    const float* x       = (const float*)d_in[0];
    const int*   gid     = (const int*)d_in[1];
    const float* w_mu    = (const float*)d_in[2];
    const float* w_sigma = (const float*)d_in[3];
    const float* b_mu    = (const float*)d_in[4];
    const float* b_sigma = (const float*)d_in[5];
    const float* eps_w   = (const float*)d_in[6];
    const float* eps_b   = (const float*)d_in[7];
    float* out = (float*)d_out;

    mld_kernel<<<NWG, 256, 0, stream>>>(x, gid, w_mu, w_sigma,
                                        b_mu, b_sigma, eps_w, eps_b, out);
}